// Round 7
// baseline (305.597 us; speedup 1.0000x reference)
//
#include <hip/hip_runtime.h>
#include <hip/hip_bf16.h>

#define CC   128
#define HH_  64
#define WW_  64
#define BB   8
#define HWSZ (HH_*WW_)      // 4096
#define CHW  (CC*HWSZ)      // 524288
#define BCHW (BB*CHW)       // 4194304
#define PAD  3
#define NP   49

typedef __attribute__((ext_vector_type(8))) short short8;
typedef __attribute__((ext_vector_type(4))) float float4v;

// ============ Kernel 0: W -> bf16 hi/lo split (into ws tail) ================
__global__ __launch_bounds__(256) void prep_w(
    const float* __restrict__ Wq, const float* __restrict__ Wk,
    const float* __restrict__ Wv,
    unsigned short* __restrict__ whi, unsigned short* __restrict__ wlo)
{
    int i = blockIdx.x * 256 + threadIdx.x;          // 0..49151
    const float* src = (i < 16384) ? Wq : (i < 32768 ? Wk : Wv);
    float f = src[i & 16383];
    __hip_bfloat16 h = __float2bfloat16(f);
    float hf = __bfloat162float(h);
    __hip_bfloat16 l = __float2bfloat16(f - hf);
    unsigned short hu, lu;
    __builtin_memcpy(&hu, &h, 2);
    __builtin_memcpy(&lu, &l, 2);
    whi[i] = hu;
    wlo[i] = lu;
}

// ============ Kernel 1: q/k/v GEMM via split-bf16 MFMA, proj-looped =========
// Grid 256 (32 px-tiles x 8 b), 256 thr (4 waves 2x2). x tile staged+converted
// ONCE, then 3 projections computed from the same LDS.
__global__ __launch_bounds__(256) void qkv_mfma(
    const float* __restrict__ x,
    const unsigned short* __restrict__ whi, const unsigned short* __restrict__ wlo,
    const float* __restrict__ bq, const float* __restrict__ bk,
    const float* __restrict__ bv, float* __restrict__ qkv)
{
    __shared__ unsigned short xT[2][128][136];   // [hi/lo][px][c], 69632 B
    const int n0g  = blockIdx.x << 7;
    const int b    = n0g >> 12;
    const int npx  = n0g & 4095;
    const int tid  = threadIdx.x;
    const int lane = tid & 63;
    const int wv   = tid >> 6;
    const int wm   = wv & 1, wn = wv >> 1;

    const float* xb = x + (size_t)b*CHW + npx;
    #pragma unroll
    for (int it = 0; it < 16; ++it) {
        int f  = tid + (it << 8);       // 0..4095
        int c  = f >> 5;
        int p4 = (f & 31) << 2;
        float4 v = *(const float4*)&xb[(size_t)c*HWSZ + p4];
        float vv[4] = {v.x, v.y, v.z, v.w};
        #pragma unroll
        for (int u = 0; u < 4; ++u) {
            __hip_bfloat16 h = __float2bfloat16(vv[u]);
            float hf = __bfloat162float(h);
            __hip_bfloat16 l = __float2bfloat16(vv[u] - hf);
            unsigned short hu, lu;
            __builtin_memcpy(&hu, &h, 2);
            __builtin_memcpy(&lu, &l, 2);
            xT[0][p4 + u][c] = hu;
            xT[1][p4 + u][c] = lu;
        }
    }
    __syncthreads();

    const int q4   = lane >> 4;
    const int kq8  = q4 << 3;
    const int mrow = lane & 15;

    for (int proj = 0; proj < 3; ++proj) {
        const float* Bp = (proj == 0) ? bq : (proj == 1 ? bk : bv);
        float4v acc[4][4];
        #pragma unroll
        for (int sm = 0; sm < 4; ++sm) {
            const int mb = wm*64 + sm*16 + q4*4;
            float4v bi;
            bi[0] = Bp[mb+0]; bi[1] = Bp[mb+1]; bi[2] = Bp[mb+2]; bi[3] = Bp[mb+3];
            #pragma unroll
            for (int sn = 0; sn < 4; ++sn) acc[sm][sn] = bi;
        }

        const unsigned short* Wh = whi + (size_t)proj*16384;
        const unsigned short* Wl = wlo + (size_t)proj*16384;

        #pragma unroll
        for (int pass = 0; pass < 3; ++pass) {
            const unsigned short* Wp = (pass == 2) ? Wl : Wh;
            const int xi = (pass == 1) ? 1 : 0;
            #pragma unroll
            for (int kc = 0; kc < 4; ++kc) {
                const int kb = kc << 5;
                short8 a[4], bf[4];
                #pragma unroll
                for (int sm = 0; sm < 4; ++sm) {
                    const int m = wm*64 + sm*16 + mrow;
                    a[sm] = *(const short8*)&Wp[(size_t)m*CC + kb + kq8];
                }
                #pragma unroll
                for (int sn = 0; sn < 4; ++sn) {
                    const int n = wn*64 + sn*16 + mrow;
                    bf[sn] = *(const short8*)&xT[xi][n][kb + kq8];
                }
                #pragma unroll
                for (int sm = 0; sm < 4; ++sm)
                    #pragma unroll
                    for (int sn = 0; sn < 4; ++sn)
                        acc[sm][sn] = __builtin_amdgcn_mfma_f32_16x16x32_bf16(
                            a[sm], bf[sn], acc[sm][sn], 0, 0, 0);
            }
        }

        float* op = qkv + (size_t)proj*BCHW + (size_t)b*CHW + npx;
        #pragma unroll
        for (int sm = 0; sm < 4; ++sm) {
            const int mb = wm*64 + sm*16 + q4*4;
            #pragma unroll
            for (int sn = 0; sn < 4; ++sn) {
                const int n = wn*64 + sn*16 + mrow;
                #pragma unroll
                for (int r = 0; r < 4; ++r)
                    op[(size_t)(mb + r)*HWSZ + n] = acc[sm][sn][r];
            }
        }
    }
}

// ================= Kernel 2: local attention v4 — no k/v LDS ================
// Block = (b, h0..h0+1), 512 thr (8 waves), lane = (csub=lane>>4, q16=lane&15).
// k/v read straight from global with 3x b128 CONTIGUOUS window [w4-4, w4+8)
// (cols w4-4..w4+7; kw[i] = col w4-4+i). L1 absorbs the overlap. Only LDS:
// logits lg + softmax. 2 barriers.
__device__ __forceinline__ void win12(const float* __restrict__ rowp,
                                      bool rv, int q16, float* kw) {
    float4 a, b, c;
    if (rv) {
        a = *(const float4*)(rowp - 4);   // cols w4-4 .. w4-1
        b = *(const float4*)(rowp);       // cols w4   .. w4+3
        c = *(const float4*)(rowp + 4);   // cols w4+4 .. w4+7
        if (q16 == 0)  { a.x = a.y = a.z = a.w = 0.f; }   // cols <0
        if (q16 == 15) { c.x = c.y = c.z = c.w = 0.f; }   // cols >=64
    } else {
        a = b = c = make_float4(0.f, 0.f, 0.f, 0.f);
    }
    kw[0]=a.x; kw[1]=a.y; kw[2]=a.z;  kw[3]=a.w;
    kw[4]=b.x; kw[5]=b.y; kw[6]=b.z;  kw[7]=b.w;
    kw[8]=c.x; kw[9]=c.y; kw[10]=c.z; kw[11]=c.w;
}

__global__ __launch_bounds__(512) void locatt(
    const float* __restrict__ qkv, float* __restrict__ out)
{
    __shared__ float lg[2][NP][64];   // 25088 B
    __shared__ float dn[2][64];

    const int blk = blockIdx.x;
    const int xsw = blk & 7;
    const int jj  = blk >> 3;
    const int b   = jj >> 2;
    const int h0  = (((xsw << 2) | (jj & 3)) << 1);   // 2-row tile origin
    const int tid  = threadIdx.x;
    const int s    = tid >> 6;     // wave 0..7
    const int lane = tid & 63;
    const int q16  = lane & 15;
    const int csub = lane >> 4;
    const int w4   = q16 << 2;

    const float* qp = qkv + (size_t)b*CHW;
    const float* kp = qkv + (size_t)BCHW + (size_t)b*CHW;
    const float* vp = qkv + (size_t)2*BCHW + (size_t)b*CHW;

    const bool do0 = (s < 7);    // k-row s serves row0 p = s*7+dx
    const bool do1 = (s >= 1);   // and row1 p = (s-1)*7+dx
    const int  hhk = h0 - PAD + s;
    const bool kv_ok = (unsigned)hhk < (unsigned)HH_;

    float acc0[7][4], acc1[7][4];
    #pragma unroll
    for (int dx = 0; dx < 7; ++dx)
        #pragma unroll
        for (int j = 0; j < 4; ++j) { acc0[dx][j] = 0.f; acc1[dx][j] = 0.f; }

    // -------- Phase A: logits (no LDS, no barriers) --------
    for (int ck = 0; ck < 8; ++ck) {
        const int c0 = ck << 4;
        #pragma unroll
        for (int ci4 = 0; ci4 < 4; ++ci4) {
            const int c = c0 + (ci4 << 2) + csub;
            float kw[12];
            win12(kp + (size_t)c*HWSZ + (long)hhk*WW_ + w4, kv_ok, q16, kw);
            const float* qc = qp + (size_t)c*HWSZ + h0*WW_ + w4;
            float4 q0v = do0 ? *(const float4*)qc
                             : make_float4(0.f, 0.f, 0.f, 0.f);
            float4 q1v = do1 ? *(const float4*)(qc + WW_)
                             : make_float4(0.f, 0.f, 0.f, 0.f);
            float q0a[4] = {q0v.x, q0v.y, q0v.z, q0v.w};
            float q1a[4] = {q1v.x, q1v.y, q1v.z, q1v.w};
            #pragma unroll
            for (int dx = 0; dx < 7; ++dx)
                #pragma unroll
                for (int j = 0; j < 4; ++j) {
                    float kvv = kw[j + dx + 1];   // col w4+j+dx-3
                    acc0[dx][j] = fmaf(q0a[j], kvv, acc0[dx][j]);
                    acc1[dx][j] = fmaf(q1a[j], kvv, acc1[dx][j]);
                }
        }
    }

    // cross-csub reduce
    #pragma unroll
    for (int dx = 0; dx < 7; ++dx)
        #pragma unroll
        for (int j = 0; j < 4; ++j) {
            acc0[dx][j] += __shfl_xor(acc0[dx][j], 16, 64);
            acc0[dx][j] += __shfl_xor(acc0[dx][j], 32, 64);
            acc1[dx][j] += __shfl_xor(acc1[dx][j], 16, 64);
            acc1[dx][j] += __shfl_xor(acc1[dx][j], 32, 64);
        }
    #pragma unroll
    for (int dx = 0; dx < 7; ++dx) {
        if ((dx & 3) == csub) {
            if (do0) *(float4*)&lg[0][s*7 + dx][w4] =
                make_float4(acc0[dx][0], acc0[dx][1], acc0[dx][2], acc0[dx][3]);
            if (do1) *(float4*)&lg[1][(s-1)*7 + dx][w4] =
                make_float4(acc1[dx][0], acc1[dx][1], acc1[dx][2], acc1[dx][3]);
        }
    }
    __syncthreads();

    // -------- Phase B: two softmaxes (OOB logits exactly 0, included) ------
    if (tid < 128) {
        const int r = tid >> 6, px = tid & 63;
        float tv[NP];
        float m = -1e30f;
        #pragma unroll
        for (int p = 0; p < NP; ++p) { tv[p] = lg[r][p][px]; m = fmaxf(m, tv[p]); }
        float d = 0.f;
        #pragma unroll
        for (int p = 0; p < NP; ++p) {
            float e = __expf(tv[p] - m);
            d += e;
            lg[r][p][px] = e;
        }
        dn[r][px] = 1.f / d;
    }
    __syncthreads();

    // -------- Phase C: y = attn . v (v from global, attn from lg) ----------
    float y0[4][4], y1[4][4];
    #pragma unroll
    for (int cg = 0; cg < 4; ++cg)
        #pragma unroll
        for (int j = 0; j < 4; ++j) { y0[cg][j] = 0.f; y1[cg][j] = 0.f; }

    const int cbase = (s << 2) + csub;
    #pragma unroll
    for (int r = 0; r < 8; ++r) {
        const int hh = h0 - PAD + r;
        const bool rv = (unsigned)hh < (unsigned)HH_;
        float vw[4][12];
        #pragma unroll
        for (int cg = 0; cg < 4; ++cg) {
            const int c = (cg << 5) + cbase;
            win12(vp + (size_t)c*HWSZ + (long)hh*WW_ + w4, rv, q16, vw[cg]);
        }
        #pragma unroll
        for (int dx = 0; dx < 7; ++dx) {
            float a0a[4], a1a[4];
            if (r < 7) {
                float4 aq = *(const float4*)&lg[0][r*7 + dx][w4];
                a0a[0]=aq.x; a0a[1]=aq.y; a0a[2]=aq.z; a0a[3]=aq.w;
            }
            if (r >= 1) {
                float4 aq = *(const float4*)&lg[1][(r-1)*7 + dx][w4];
                a1a[0]=aq.x; a1a[1]=aq.y; a1a[2]=aq.z; a1a[3]=aq.w;
            }
            #pragma unroll
            for (int cg = 0; cg < 4; ++cg)
                #pragma unroll
                for (int j = 0; j < 4; ++j) {
                    float vv = vw[cg][j + dx + 1];
                    if (r < 7)  y0[cg][j] = fmaf(a0a[j], vv, y0[cg][j]);
                    if (r >= 1) y1[cg][j] = fmaf(a1a[j], vv, y1[cg][j]);
                }
        }
    }

    const float4 s0v = *(const float4*)&dn[0][w4];
    const float4 s1v = *(const float4*)&dn[1][w4];
    const float s0a[4] = {s0v.x, s0v.y, s0v.z, s0v.w};
    const float s1a[4] = {s1v.x, s1v.y, s1v.z, s1v.w};
    #pragma unroll
    for (int cg = 0; cg < 4; ++cg) {
        const int c = (cg << 5) + cbase;
        float* op = out + (size_t)b*CHW + (size_t)c*HWSZ + (size_t)h0*WW_ + w4;
        float4 o0 = make_float4(y0[cg][0]*s0a[0], y0[cg][1]*s0a[1],
                                y0[cg][2]*s0a[2], y0[cg][3]*s0a[3]);
        float4 o1 = make_float4(y1[cg][0]*s1a[0], y1[cg][1]*s1a[1],
                                y1[cg][2]*s1a[2], y1[cg][3]*s1a[3]);
        *(float4*)op         = o0;
        *(float4*)(op + WW_) = o1;
    }
}

extern "C" void kernel_launch(void* const* d_in, const int* in_sizes, int n_in,
                              void* d_out, int out_size, void* d_ws, size_t ws_size,
                              hipStream_t stream) {
    const float* x  = (const float*)d_in[0];
    const float* Wq = (const float*)d_in[1];
    const float* bq = (const float*)d_in[2];
    const float* Wk = (const float*)d_in[3];
    const float* bk = (const float*)d_in[4];
    const float* Wv = (const float*)d_in[5];
    const float* bv = (const float*)d_in[6];
    float* out = (float*)d_out;
    float* qkv = (float*)d_ws;                       // 50.3 MB
    unsigned short* whi = (unsigned short*)(qkv + (size_t)3*BCHW);  // 96 KB
    unsigned short* wlo = whi + 3*16384;                            // 96 KB

    prep_w  <<<192, 256, 0, stream>>>(Wq, Wk, Wv, whi, wlo);
    qkv_mfma<<<256, 256, 0, stream>>>(x, whi, wlo, bq, bk, bv, qkv);
    locatt  <<<256, 512, 0, stream>>>(qkv, out);
}

// Round 8
// 171.314 us; speedup vs baseline: 1.7838x; 1.7838x over previous
//
#include <hip/hip_runtime.h>
#include <hip/hip_bf16.h>

#define CC   128
#define HH_  64
#define WW_  64
#define BB   8
#define HWSZ (HH_*WW_)      // 4096
#define CHW  (CC*HWSZ)      // 524288
#define BCHW (BB*CHW)       // 4194304
#define PAD  3
#define NP   49

typedef __attribute__((ext_vector_type(8))) short short8;
typedef __attribute__((ext_vector_type(8))) unsigned short ushort8;
typedef __attribute__((ext_vector_type(4))) float float4v;

__device__ __forceinline__ void split_bf16(float f, unsigned short& hu,
                                           unsigned short& lu) {
    __hip_bfloat16 h = __float2bfloat16(f);
    float hf = __bfloat162float(h);
    __hip_bfloat16 l = __float2bfloat16(f - hf);
    __builtin_memcpy(&hu, &h, 2);
    __builtin_memcpy(&lu, &l, 2);
}

// ============ Kernel 0: W -> bf16 hi/lo split ===============================
__global__ __launch_bounds__(256) void prep_w(
    const float* __restrict__ Wq, const float* __restrict__ Wk,
    const float* __restrict__ Wv,
    unsigned short* __restrict__ whi, unsigned short* __restrict__ wlo)
{
    int i = blockIdx.x * 256 + threadIdx.x;          // 0..49151
    const float* src = (i < 16384) ? Wq : (i < 32768 ? Wk : Wv);
    float f = src[i & 16383];
    split_bf16(f, whi[i], wlo[i]);
}

// ============ Kernel 0b: x -> transposed bf16 hi/lo xT[b][px][c] ============
// Block = (b, 128-px chunk). Read x[c][px] coalesced, LDS transpose, write
// xT rows (c contiguous) coalesced.
__global__ __launch_bounds__(256) void prep_x(
    const float* __restrict__ x,
    unsigned short* __restrict__ xhiT, unsigned short* __restrict__ xloT)
{
    __shared__ __align__(16) unsigned short sh[128][136];  // [px][c]
    __shared__ __align__(16) unsigned short sl[128][136];
    const int b   = blockIdx.x >> 5;
    const int px0 = (blockIdx.x & 31) << 7;
    const int tid = threadIdx.x;

    const float* xb = x + (size_t)b*CHW + px0;
    #pragma unroll
    for (int it = 0; it < 16; ++it) {
        int f  = tid + (it << 8);        // 0..4095 = 128c x 32 quads
        int c  = f >> 5;
        int q4 = (f & 31) << 2;
        float4 v = *(const float4*)&xb[(size_t)c*HWSZ + q4];
        float vv[4] = {v.x, v.y, v.z, v.w};
        #pragma unroll
        for (int u = 0; u < 4; ++u)
            split_bf16(vv[u], sh[q4 + u][c], sl[q4 + u][c]);
    }
    __syncthreads();

    unsigned short* oh = xhiT + ((size_t)b*HWSZ + px0) * CC;
    unsigned short* ol = xloT + ((size_t)b*HWSZ + px0) * CC;
    #pragma unroll
    for (int it = 0; it < 8; ++it) {
        int g  = tid + (it << 8);        // 0..2047 = 128px x 16 c8-groups
        int px = g >> 4;
        int c8 = (g & 15) << 3;
        *(ushort8*)&oh[(size_t)px*CC + c8] = *(const ushort8*)&sh[px][c8];
        *(ushort8*)&ol[(size_t)px*CC + c8] = *(const ushort8*)&sl[px][c8];
    }
}

// ============ Kernel 1: q/k/v GEMM — LDS-free split-bf16 MFMA ===============
// Grid (64 px-tiles, 8 b, 3 proj) = 1536 blocks (6/CU). 256 thr = 4 waves 2x2;
// wave tile 64m x 32n; K' = 3 passes x 128 (hi*hi, hi*lo, lo*hi). A-frags from
// bf16 W (L2-hot), B-frags from xT[b][px][c] (b128, unique per block).
__global__ __launch_bounds__(256) void qkv_mfma(
    const unsigned short* __restrict__ whi, const unsigned short* __restrict__ wlo,
    const unsigned short* __restrict__ xhiT, const unsigned short* __restrict__ xloT,
    const float* __restrict__ bq, const float* __restrict__ bk,
    const float* __restrict__ bv, float* __restrict__ qkv)
{
    const int npx0 = blockIdx.x << 6;
    const int b    = blockIdx.y;
    const int proj = blockIdx.z;
    const int tid  = threadIdx.x;
    const int lane = tid & 63;
    const int wv   = tid >> 6;
    const int wm   = wv & 1, wn = wv >> 1;
    const int row16 = lane & 15;
    const int q4    = lane >> 4;
    const int kq8   = q4 << 3;

    const unsigned short* Wh = whi + (size_t)proj*16384;
    const unsigned short* Wl = wlo + (size_t)proj*16384;
    const unsigned short* Xh = xhiT + ((size_t)b*HWSZ + npx0) * CC;
    const unsigned short* Xl = xloT + ((size_t)b*HWSZ + npx0) * CC;

    const float* Bp = (proj == 0) ? bq : (proj == 1 ? bk : bv);
    float4v acc[4][2];
    #pragma unroll
    for (int sm = 0; sm < 4; ++sm) {
        const int mb = wm*64 + sm*16 + q4*4;
        float4v bi;
        bi[0] = Bp[mb+0]; bi[1] = Bp[mb+1]; bi[2] = Bp[mb+2]; bi[3] = Bp[mb+3];
        acc[sm][0] = bi; acc[sm][1] = bi;
    }

    for (int pass = 0; pass < 3; ++pass) {
        const unsigned short* Wp = (pass == 2) ? Wl : Wh;
        const unsigned short* Xp = (pass == 1) ? Xl : Xh;
        #pragma unroll
        for (int kc = 0; kc < 4; ++kc) {
            const int kb = kc << 5;
            short8 a[4], bb[2];
            #pragma unroll
            for (int sm = 0; sm < 4; ++sm) {
                const int m = wm*64 + sm*16 + row16;
                a[sm] = *(const short8*)&Wp[(size_t)m*CC + kb + kq8];
            }
            #pragma unroll
            for (int sn = 0; sn < 2; ++sn) {
                const int n = wn*32 + sn*16 + row16;
                bb[sn] = *(const short8*)&Xp[(size_t)n*CC + kb + kq8];
            }
            #pragma unroll
            for (int sm = 0; sm < 4; ++sm)
                #pragma unroll
                for (int sn = 0; sn < 2; ++sn)
                    acc[sm][sn] = __builtin_amdgcn_mfma_f32_16x16x32_bf16(
                        a[sm], bb[sn], acc[sm][sn], 0, 0, 0);
        }
    }

    float* op = qkv + (size_t)proj*BCHW + (size_t)b*CHW + npx0;
    #pragma unroll
    for (int sm = 0; sm < 4; ++sm) {
        const int mb = wm*64 + sm*16 + q4*4;
        #pragma unroll
        for (int sn = 0; sn < 2; ++sn) {
            const int n = wn*32 + sn*16 + row16;
            #pragma unroll
            for (int r = 0; r < 4; ++r)
                op[(size_t)(mb + r)*HWSZ + n] = acc[sm][sn][r];
        }
    }
}

// ================= Kernel 2: local attention v5 — no k/v LDS, no spill ======
// Identical math to v4 (verified). Phase C r-loop is NOT unrolled (runtime r,
// wave-uniform branches) so only one r's v-windows are live -> no VGPR spill.
__device__ __forceinline__ void win12(const float* __restrict__ rowp,
                                      bool rv, int q16, float* kw) {
    float4 a, b, c;
    if (rv) {
        a = *(const float4*)(rowp - 4);   // cols w4-4 .. w4-1
        b = *(const float4*)(rowp);       // cols w4   .. w4+3
        c = *(const float4*)(rowp + 4);   // cols w4+4 .. w4+7
        if (q16 == 0)  { a.x = a.y = a.z = a.w = 0.f; }   // cols <0
        if (q16 == 15) { c.x = c.y = c.z = c.w = 0.f; }   // cols >=64
    } else {
        a = b = c = make_float4(0.f, 0.f, 0.f, 0.f);
    }
    kw[0]=a.x; kw[1]=a.y; kw[2]=a.z;  kw[3]=a.w;
    kw[4]=b.x; kw[5]=b.y; kw[6]=b.z;  kw[7]=b.w;
    kw[8]=c.x; kw[9]=c.y; kw[10]=c.z; kw[11]=c.w;
}

__global__ __launch_bounds__(512) void locatt(
    const float* __restrict__ qkv, float* __restrict__ out)
{
    __shared__ float lg[2][NP][64];   // 25088 B
    __shared__ float dn[2][64];

    const int blk = blockIdx.x;
    const int xsw = blk & 7;
    const int jj  = blk >> 3;
    const int b   = jj >> 2;
    const int h0  = (((xsw << 2) | (jj & 3)) << 1);   // 2-row tile origin
    const int tid  = threadIdx.x;
    const int s    = tid >> 6;     // wave 0..7
    const int lane = tid & 63;
    const int q16  = lane & 15;
    const int csub = lane >> 4;
    const int w4   = q16 << 2;

    const float* qp = qkv + (size_t)b*CHW;
    const float* kp = qkv + (size_t)BCHW + (size_t)b*CHW;
    const float* vp = qkv + (size_t)2*BCHW + (size_t)b*CHW;

    const bool do0 = (s < 7);
    const bool do1 = (s >= 1);
    const int  hhk = h0 - PAD + s;
    const bool kv_ok = (unsigned)hhk < (unsigned)HH_;

    float acc0[7][4], acc1[7][4];
    #pragma unroll
    for (int dx = 0; dx < 7; ++dx)
        #pragma unroll
        for (int j = 0; j < 4; ++j) { acc0[dx][j] = 0.f; acc1[dx][j] = 0.f; }

    // -------- Phase A: logits (no LDS, no barriers) --------
    for (int ck = 0; ck < 8; ++ck) {
        const int c0 = ck << 4;
        #pragma unroll
        for (int ci4 = 0; ci4 < 4; ++ci4) {
            const int c = c0 + (ci4 << 2) + csub;
            float kw[12];
            win12(kp + (size_t)c*HWSZ + (long)hhk*WW_ + w4, kv_ok, q16, kw);
            const float* qc = qp + (size_t)c*HWSZ + h0*WW_ + w4;
            float4 q0v = do0 ? *(const float4*)qc
                             : make_float4(0.f, 0.f, 0.f, 0.f);
            float4 q1v = do1 ? *(const float4*)(qc + WW_)
                             : make_float4(0.f, 0.f, 0.f, 0.f);
            float q0a[4] = {q0v.x, q0v.y, q0v.z, q0v.w};
            float q1a[4] = {q1v.x, q1v.y, q1v.z, q1v.w};
            #pragma unroll
            for (int dx = 0; dx < 7; ++dx)
                #pragma unroll
                for (int j = 0; j < 4; ++j) {
                    float kvv = kw[j + dx + 1];   // col w4+j+dx-3
                    acc0[dx][j] = fmaf(q0a[j], kvv, acc0[dx][j]);
                    acc1[dx][j] = fmaf(q1a[j], kvv, acc1[dx][j]);
                }
        }
    }

    #pragma unroll
    for (int dx = 0; dx < 7; ++dx)
        #pragma unroll
        for (int j = 0; j < 4; ++j) {
            acc0[dx][j] += __shfl_xor(acc0[dx][j], 16, 64);
            acc0[dx][j] += __shfl_xor(acc0[dx][j], 32, 64);
            acc1[dx][j] += __shfl_xor(acc1[dx][j], 16, 64);
            acc1[dx][j] += __shfl_xor(acc1[dx][j], 32, 64);
        }
    #pragma unroll
    for (int dx = 0; dx < 7; ++dx) {
        if ((dx & 3) == csub) {
            if (do0) *(float4*)&lg[0][s*7 + dx][w4] =
                make_float4(acc0[dx][0], acc0[dx][1], acc0[dx][2], acc0[dx][3]);
            if (do1) *(float4*)&lg[1][(s-1)*7 + dx][w4] =
                make_float4(acc1[dx][0], acc1[dx][1], acc1[dx][2], acc1[dx][3]);
        }
    }
    __syncthreads();

    // -------- Phase B: two softmaxes (OOB logits exactly 0, included) ------
    if (tid < 128) {
        const int r = tid >> 6, px = tid & 63;
        float tv[NP];
        float m = -1e30f;
        #pragma unroll
        for (int p = 0; p < NP; ++p) { tv[p] = lg[r][p][px]; m = fmaxf(m, tv[p]); }
        float d = 0.f;
        #pragma unroll
        for (int p = 0; p < NP; ++p) {
            float e = __expf(tv[p] - m);
            d += e;
            lg[r][p][px] = e;
        }
        dn[r][px] = 1.f / d;
    }
    __syncthreads();

    // -------- Phase C: y = attn . v  (r-loop NOT unrolled: no spill) -------
    float y0[4][4], y1[4][4];
    #pragma unroll
    for (int cg = 0; cg < 4; ++cg)
        #pragma unroll
        for (int j = 0; j < 4; ++j) { y0[cg][j] = 0.f; y1[cg][j] = 0.f; }

    const int cbase = (s << 2) + csub;
    #pragma unroll 1
    for (int r = 0; r < 8; ++r) {
        const int hh = h0 - PAD + r;
        const bool rv = (unsigned)hh < (unsigned)HH_;
        float vw[4][12];
        #pragma unroll
        for (int cg = 0; cg < 4; ++cg) {
            const int c = (cg << 5) + cbase;
            win12(vp + (size_t)c*HWSZ + (long)hh*WW_ + w4, rv, q16, vw[cg]);
        }
        const bool r0 = (r < 7);    // wave-uniform
        const bool r1 = (r >= 1);
        #pragma unroll
        for (int dx = 0; dx < 7; ++dx) {
            if (r0) {
                float4 aq = *(const float4*)&lg[0][r*7 + dx][w4];
                float aa[4] = {aq.x, aq.y, aq.z, aq.w};
                #pragma unroll
                for (int cg = 0; cg < 4; ++cg)
                    #pragma unroll
                    for (int j = 0; j < 4; ++j)
                        y0[cg][j] = fmaf(aa[j], vw[cg][j + dx + 1], y0[cg][j]);
            }
            if (r1) {
                float4 aq = *(const float4*)&lg[1][(r-1)*7 + dx][w4];
                float aa[4] = {aq.x, aq.y, aq.z, aq.w};
                #pragma unroll
                for (int cg = 0; cg < 4; ++cg)
                    #pragma unroll
                    for (int j = 0; j < 4; ++j)
                        y1[cg][j] = fmaf(aa[j], vw[cg][j + dx + 1], y1[cg][j]);
            }
        }
    }

    const float4 s0v = *(const float4*)&dn[0][w4];
    const float4 s1v = *(const float4*)&dn[1][w4];
    const float s0a[4] = {s0v.x, s0v.y, s0v.z, s0v.w};
    const float s1a[4] = {s1v.x, s1v.y, s1v.z, s1v.w};
    #pragma unroll
    for (int cg = 0; cg < 4; ++cg) {
        const int c = (cg << 5) + cbase;
        float* op = out + (size_t)b*CHW + (size_t)c*HWSZ + (size_t)h0*WW_ + w4;
        float4 o0 = make_float4(y0[cg][0]*s0a[0], y0[cg][1]*s0a[1],
                                y0[cg][2]*s0a[2], y0[cg][3]*s0a[3]);
        float4 o1 = make_float4(y1[cg][0]*s1a[0], y1[cg][1]*s1a[1],
                                y1[cg][2]*s1a[2], y1[cg][3]*s1a[3]);
        *(float4*)op         = o0;
        *(float4*)(op + WW_) = o1;
    }
}

extern "C" void kernel_launch(void* const* d_in, const int* in_sizes, int n_in,
                              void* d_out, int out_size, void* d_ws, size_t ws_size,
                              hipStream_t stream) {
    const float* x  = (const float*)d_in[0];
    const float* Wq = (const float*)d_in[1];
    const float* bq = (const float*)d_in[2];
    const float* Wk = (const float*)d_in[3];
    const float* bk = (const float*)d_in[4];
    const float* Wv = (const float*)d_in[5];
    const float* bv = (const float*)d_in[6];
    float* out = (float*)d_out;

    // ws layout: qkv (50.3 MB) | whi,wlo (2x96 KB) | xhiT,xloT (2x8.4 MB)
    float* qkv = (float*)d_ws;
    unsigned short* us   = (unsigned short*)(qkv + (size_t)3*BCHW);
    unsigned short* whi  = us;
    unsigned short* wlo  = whi + 3*16384;
    unsigned short* xhiT = wlo + 3*16384;
    unsigned short* xloT = xhiT + (size_t)BB*HWSZ*CC;

    prep_w  <<<192, 256, 0, stream>>>(Wq, Wk, Wv, whi, wlo);
    prep_x  <<<256, 256, 0, stream>>>(x, xhiT, xloT);
    qkv_mfma<<<dim3(64, 8, 3), 256, 0, stream>>>(whi, wlo, xhiT, xloT,
                                                 bq, bk, bv, qkv);
    locatt  <<<256, 512, 0, stream>>>(qkv, out);
}

// Round 9
// 166.900 us; speedup vs baseline: 1.8310x; 1.0264x over previous
//
#include <hip/hip_runtime.h>
#include <hip/hip_bf16.h>

#define CC   128
#define HH_  64
#define WW_  64
#define BB   8
#define HWSZ (HH_*WW_)      // 4096
#define CHW  (CC*HWSZ)      // 524288
#define BCHW (BB*CHW)       // 4194304
#define PAD  3
#define NP   49

typedef __attribute__((ext_vector_type(8))) short short8;
typedef __attribute__((ext_vector_type(4))) float float4v;

__device__ __forceinline__ void split_bf16(float f, unsigned short& hu,
                                           unsigned short& lu) {
    __hip_bfloat16 h = __float2bfloat16(f);
    float hf = __bfloat162float(h);
    __hip_bfloat16 l = __float2bfloat16(f - hf);
    __builtin_memcpy(&hu, &h, 2);
    __builtin_memcpy(&lu, &l, 2);
}

// ============ Kernel 0: W -> bf16 hi/lo split ===============================
__global__ __launch_bounds__(256) void prep_w(
    const float* __restrict__ Wq, const float* __restrict__ Wk,
    const float* __restrict__ Wv,
    unsigned short* __restrict__ whi, unsigned short* __restrict__ wlo)
{
    int i = blockIdx.x * 256 + threadIdx.x;          // 0..49151
    const float* src = (i < 16384) ? Wq : (i < 32768 ? Wk : Wv);
    float f = src[i & 16383];
    split_bf16(f, whi[i], wlo[i]);
}

// ============ Kernel 1: q/k/v GEMM — split-bf16 MFMA, in-kernel transpose ===
// Grid (64 px-tiles, 8 b) = 512 blocks (2/CU). 256 thr = 4 waves 2x2.
// Block tile 128 out x 64 px, proj-looped (x converted ONCE). LDS 34.8 KB.
// A-frags preloaded per pass (16 outstanding b128 VMEM), B-frags ds_read_b128.
__global__ __launch_bounds__(256) void qkv_mfma(
    const float* __restrict__ x,
    const unsigned short* __restrict__ whi, const unsigned short* __restrict__ wlo,
    const float* __restrict__ bq, const float* __restrict__ bk,
    const float* __restrict__ bv, float* __restrict__ qkv)
{
    __shared__ __align__(16) unsigned short sh[64][136];   // [px][c] hi
    __shared__ __align__(16) unsigned short sl[64][136];   // [px][c] lo
    const int px0  = blockIdx.x << 6;
    const int b    = blockIdx.y;
    const int tid  = threadIdx.x;
    const int lane = tid & 63;
    const int wv   = tid >> 6;
    const int wm   = wv & 1, wn = wv >> 1;
    const int row16 = lane & 15;
    const int q4    = lane >> 4;
    const int kq8   = q4 << 3;

    // ---- stage + convert + transpose x tile: 128 c x 64 px ----
    const float* xb = x + (size_t)b*CHW + px0;
    #pragma unroll
    for (int it = 0; it < 8; ++it) {
        int f   = tid + (it << 8);      // 0..2047 = 128c x 16 quads
        int c   = f >> 4;
        int p4  = (f & 15) << 2;
        float4 v = *(const float4*)&xb[(size_t)c*HWSZ + p4];
        float vv[4] = {v.x, v.y, v.z, v.w};
        #pragma unroll
        for (int u = 0; u < 4; ++u)
            split_bf16(vv[u], sh[p4 + u][c], sl[p4 + u][c]);
    }
    __syncthreads();

    for (int proj = 0; proj < 3; ++proj) {
        const float* Bp = (proj == 0) ? bq : (proj == 1 ? bk : bv);
        float4v acc[4][2];
        #pragma unroll
        for (int sm = 0; sm < 4; ++sm) {
            const int mb = wm*64 + sm*16 + q4*4;
            float4v bi;
            bi[0] = Bp[mb+0]; bi[1] = Bp[mb+1]; bi[2] = Bp[mb+2]; bi[3] = Bp[mb+3];
            acc[sm][0] = bi; acc[sm][1] = bi;
        }

        const unsigned short* Wh = whi + (size_t)proj*16384;
        const unsigned short* Wl = wlo + (size_t)proj*16384;

        #pragma unroll
        for (int pass = 0; pass < 3; ++pass) {
            const unsigned short* Wp = (pass == 2) ? Wl : Wh;
            const unsigned short (*Xp)[136] = (pass == 1) ? sl : sh;
            // preload all A-frags for this pass (16 VMEM b128 in flight)
            short8 a[4][4];
            #pragma unroll
            for (int kc = 0; kc < 4; ++kc)
                #pragma unroll
                for (int sm = 0; sm < 4; ++sm) {
                    const int m = wm*64 + sm*16 + row16;
                    a[kc][sm] = *(const short8*)&Wp[(size_t)m*CC + (kc<<5) + kq8];
                }
            #pragma unroll
            for (int kc = 0; kc < 4; ++kc) {
                const int kb = kc << 5;
                short8 bb[2];
                #pragma unroll
                for (int sn = 0; sn < 2; ++sn) {
                    const int n = wn*32 + sn*16 + row16;
                    bb[sn] = *(const short8*)&Xp[n][kb + kq8];
                }
                #pragma unroll
                for (int sm = 0; sm < 4; ++sm)
                    #pragma unroll
                    for (int sn = 0; sn < 2; ++sn)
                        acc[sm][sn] = __builtin_amdgcn_mfma_f32_16x16x32_bf16(
                            a[kc][sm], bb[sn], acc[sm][sn], 0, 0, 0);
            }
        }

        float* op = qkv + (size_t)proj*BCHW + (size_t)b*CHW + px0;
        #pragma unroll
        for (int sm = 0; sm < 4; ++sm) {
            const int mb = wm*64 + sm*16 + q4*4;
            #pragma unroll
            for (int sn = 0; sn < 2; ++sn) {
                const int n = wn*32 + sn*16 + row16;
                #pragma unroll
                for (int r = 0; r < 4; ++r)
                    op[(size_t)(mb + r)*HWSZ + n] = acc[sm][sn][r];
            }
        }
    }
}

// ================= Kernel 2: local attention v6 — 16 waves ==================
// Block = (b, h0..h0+1), 1024 thr (16 waves) for 50% occupancy (was 25%).
// wave = (s = k-row 0..7, ch = channel-half). Same verified math as v5.
// Phase A: wave (s,ch) accumulates 64 channels; lg merged write-then-add.
// Phase C: thread owns 2 channels (cb2, cb2+64) x 4 px; r-loop not unrolled.
__device__ __forceinline__ void win12(const float* __restrict__ rowp,
                                      bool rv, int q16, float* kw) {
    float4 a, b, c;
    if (rv) {
        a = *(const float4*)(rowp - 4);   // cols w4-4 .. w4-1
        b = *(const float4*)(rowp);       // cols w4   .. w4+3
        c = *(const float4*)(rowp + 4);   // cols w4+4 .. w4+7
        if (q16 == 0)  { a.x = a.y = a.z = a.w = 0.f; }   // cols <0
        if (q16 == 15) { c.x = c.y = c.z = c.w = 0.f; }   // cols >=64
    } else {
        a = b = c = make_float4(0.f, 0.f, 0.f, 0.f);
    }
    kw[0]=a.x; kw[1]=a.y; kw[2]=a.z;  kw[3]=a.w;
    kw[4]=b.x; kw[5]=b.y; kw[6]=b.z;  kw[7]=b.w;
    kw[8]=c.x; kw[9]=c.y; kw[10]=c.z; kw[11]=c.w;
}

__global__ __launch_bounds__(1024) void locatt(
    const float* __restrict__ qkv, float* __restrict__ out)
{
    __shared__ float lg[2][NP][64];   // 25088 B
    __shared__ float dn[2][64];

    const int blk = blockIdx.x;
    const int xsw = blk & 7;
    const int jj  = blk >> 3;
    const int b   = jj >> 2;
    const int h0  = (((xsw << 2) | (jj & 3)) << 1);   // 2-row tile origin
    const int tid  = threadIdx.x;
    const int wid  = tid >> 6;     // wave 0..15
    const int s    = wid & 7;      // k-row
    const int ch   = wid >> 3;     // channel half
    const int lane = tid & 63;
    const int q16  = lane & 15;
    const int csub = lane >> 4;
    const int w4   = q16 << 2;

    const float* qp = qkv + (size_t)b*CHW;
    const float* kp = qkv + (size_t)BCHW + (size_t)b*CHW;
    const float* vp = qkv + (size_t)2*BCHW + (size_t)b*CHW;

    const bool do0 = (s < 7);
    const bool do1 = (s >= 1);
    const int  hhk = h0 - PAD + s;
    const bool kv_ok = (unsigned)hhk < (unsigned)HH_;

    float acc0[7][4], acc1[7][4];
    #pragma unroll
    for (int dx = 0; dx < 7; ++dx)
        #pragma unroll
        for (int j = 0; j < 4; ++j) { acc0[dx][j] = 0.f; acc1[dx][j] = 0.f; }

    // -------- Phase A: logits; wave (s,ch) does channels ch*64..+63 --------
    for (int ck = 0; ck < 4; ++ck) {
        const int c0 = (ch << 6) + (ck << 4);
        #pragma unroll
        for (int ci4 = 0; ci4 < 4; ++ci4) {
            const int c = c0 + (ci4 << 2) + csub;
            float kw[12];
            win12(kp + (size_t)c*HWSZ + (long)hhk*WW_ + w4, kv_ok, q16, kw);
            const float* qc = qp + (size_t)c*HWSZ + h0*WW_ + w4;
            float4 q0v = do0 ? *(const float4*)qc
                             : make_float4(0.f, 0.f, 0.f, 0.f);
            float4 q1v = do1 ? *(const float4*)(qc + WW_)
                             : make_float4(0.f, 0.f, 0.f, 0.f);
            float q0a[4] = {q0v.x, q0v.y, q0v.z, q0v.w};
            float q1a[4] = {q1v.x, q1v.y, q1v.z, q1v.w};
            #pragma unroll
            for (int dx = 0; dx < 7; ++dx)
                #pragma unroll
                for (int j = 0; j < 4; ++j) {
                    float kvv = kw[j + dx + 1];   // col w4+j+dx-3
                    acc0[dx][j] = fmaf(q0a[j], kvv, acc0[dx][j]);
                    acc1[dx][j] = fmaf(q1a[j], kvv, acc1[dx][j]);
                }
        }
    }

    #pragma unroll
    for (int dx = 0; dx < 7; ++dx)
        #pragma unroll
        for (int j = 0; j < 4; ++j) {
            acc0[dx][j] += __shfl_xor(acc0[dx][j], 16, 64);
            acc0[dx][j] += __shfl_xor(acc0[dx][j], 32, 64);
            acc1[dx][j] += __shfl_xor(acc1[dx][j], 16, 64);
            acc1[dx][j] += __shfl_xor(acc1[dx][j], 32, 64);
        }

    // two-stage lg merge: ch=0 writes, ch=1 adds
    if (ch == 0) {
        #pragma unroll
        for (int dx = 0; dx < 7; ++dx) {
            if ((dx & 3) == csub) {
                if (do0) *(float4*)&lg[0][s*7 + dx][w4] =
                    make_float4(acc0[dx][0], acc0[dx][1], acc0[dx][2], acc0[dx][3]);
                if (do1) *(float4*)&lg[1][(s-1)*7 + dx][w4] =
                    make_float4(acc1[dx][0], acc1[dx][1], acc1[dx][2], acc1[dx][3]);
            }
        }
    }
    __syncthreads();
    if (ch == 1) {
        #pragma unroll
        for (int dx = 0; dx < 7; ++dx) {
            if ((dx & 3) == csub) {
                if (do0) {
                    float4 t = *(const float4*)&lg[0][s*7 + dx][w4];
                    t.x += acc0[dx][0]; t.y += acc0[dx][1];
                    t.z += acc0[dx][2]; t.w += acc0[dx][3];
                    *(float4*)&lg[0][s*7 + dx][w4] = t;
                }
                if (do1) {
                    float4 t = *(const float4*)&lg[1][(s-1)*7 + dx][w4];
                    t.x += acc1[dx][0]; t.y += acc1[dx][1];
                    t.z += acc1[dx][2]; t.w += acc1[dx][3];
                    *(float4*)&lg[1][(s-1)*7 + dx][w4] = t;
                }
            }
        }
    }
    __syncthreads();

    // -------- Phase B: two softmaxes (OOB logits exactly 0, included) ------
    if (tid < 128) {
        const int r = tid >> 6, px = tid & 63;
        float tv[NP];
        float m = -1e30f;
        #pragma unroll
        for (int p = 0; p < NP; ++p) { tv[p] = lg[r][p][px]; m = fmaxf(m, tv[p]); }
        float d = 0.f;
        #pragma unroll
        for (int p = 0; p < NP; ++p) {
            float e = __expf(tv[p] - m);
            d += e;
            lg[r][p][px] = e;
        }
        dn[r][px] = 1.f / d;
    }
    __syncthreads();

    // -------- Phase C: y = attn . v; thread owns channels cb2, cb2+64 ------
    float y0[2][4], y1[2][4];
    #pragma unroll
    for (int cg = 0; cg < 2; ++cg)
        #pragma unroll
        for (int j = 0; j < 4; ++j) { y0[cg][j] = 0.f; y1[cg][j] = 0.f; }

    const int cb2 = (wid << 2) + csub;   // 0..63
    #pragma unroll 1
    for (int r = 0; r < 8; ++r) {
        const int hh = h0 - PAD + r;
        const bool rv = (unsigned)hh < (unsigned)HH_;
        float vw[2][12];
        #pragma unroll
        for (int cg = 0; cg < 2; ++cg) {
            const int c = cb2 + (cg << 6);
            win12(vp + (size_t)c*HWSZ + (long)hh*WW_ + w4, rv, q16, vw[cg]);
        }
        const bool r0 = (r < 7);    // wave-uniform
        const bool r1 = (r >= 1);
        #pragma unroll
        for (int dx = 0; dx < 7; ++dx) {
            if (r0) {
                float4 aq = *(const float4*)&lg[0][r*7 + dx][w4];
                float aa[4] = {aq.x, aq.y, aq.z, aq.w};
                #pragma unroll
                for (int cg = 0; cg < 2; ++cg)
                    #pragma unroll
                    for (int j = 0; j < 4; ++j)
                        y0[cg][j] = fmaf(aa[j], vw[cg][j + dx + 1], y0[cg][j]);
            }
            if (r1) {
                float4 aq = *(const float4*)&lg[1][(r-1)*7 + dx][w4];
                float aa[4] = {aq.x, aq.y, aq.z, aq.w};
                #pragma unroll
                for (int cg = 0; cg < 2; ++cg)
                    #pragma unroll
                    for (int j = 0; j < 4; ++j)
                        y1[cg][j] = fmaf(aa[j], vw[cg][j + dx + 1], y1[cg][j]);
            }
        }
    }

    const float4 s0v = *(const float4*)&dn[0][w4];
    const float4 s1v = *(const float4*)&dn[1][w4];
    const float s0a[4] = {s0v.x, s0v.y, s0v.z, s0v.w};
    const float s1a[4] = {s1v.x, s1v.y, s1v.z, s1v.w};
    #pragma unroll
    for (int cg = 0; cg < 2; ++cg) {
        const int c = cb2 + (cg << 6);
        float* op = out + (size_t)b*CHW + (size_t)c*HWSZ + (size_t)h0*WW_ + w4;
        float4 o0 = make_float4(y0[cg][0]*s0a[0], y0[cg][1]*s0a[1],
                                y0[cg][2]*s0a[2], y0[cg][3]*s0a[3]);
        float4 o1 = make_float4(y1[cg][0]*s1a[0], y1[cg][1]*s1a[1],
                                y1[cg][2]*s1a[2], y1[cg][3]*s1a[3]);
        *(float4*)op         = o0;
        *(float4*)(op + WW_) = o1;
    }
}

extern "C" void kernel_launch(void* const* d_in, const int* in_sizes, int n_in,
                              void* d_out, int out_size, void* d_ws, size_t ws_size,
                              hipStream_t stream) {
    const float* x  = (const float*)d_in[0];
    const float* Wq = (const float*)d_in[1];
    const float* bq = (const float*)d_in[2];
    const float* Wk = (const float*)d_in[3];
    const float* bk = (const float*)d_in[4];
    const float* Wv = (const float*)d_in[5];
    const float* bv = (const float*)d_in[6];
    float* out = (float*)d_out;

    // ws layout: qkv (50.3 MB) | whi,wlo (2x96 KB)
    float* qkv = (float*)d_ws;
    unsigned short* whi = (unsigned short*)(qkv + (size_t)3*BCHW);
    unsigned short* wlo = whi + 3*16384;

    prep_w  <<<192, 256, 0, stream>>>(Wq, Wk, Wv, whi, wlo);
    qkv_mfma<<<dim3(64, 8), 256, 0, stream>>>(x, whi, wlo, bq, bk, bv, qkv);
    locatt  <<<256, 1024, 0, stream>>>(qkv, out);
}